// Round 3
// baseline (475.556 us; speedup 1.0000x reference)
//
#include <hip/hip_runtime.h>
#include <cstdint>

typedef unsigned short u16;
typedef __attribute__((ext_vector_type(8))) __bf16 bf16x8;
typedef __attribute__((ext_vector_type(4))) float f32x4;

#define MFMA16(a, b, c) __builtin_amdgcn_mfma_f32_16x16x32_bf16((a), (b), (c), 0, 0, 0)

__device__ __forceinline__ u16 f2b(float f) {
    union { float f; unsigned u; } v; v.f = f;
    unsigned r = v.u + 0x7fffu + ((v.u >> 16) & 1u);
    return (u16)(r >> 16);
}
__device__ __forceinline__ float b2f(u16 h) {
    union { unsigned u; float f; } v; v.u = ((unsigned)h) << 16; return v.f;
}
__device__ __forceinline__ float fast_rcp(float x) { return __builtin_amdgcn_rcpf(x); }
// mish(x) = x * tanh(softplus(x)) = x * (u^2-1)/(u^2+1), u = 1+e^x
__device__ __forceinline__ float mish_f(float x) {
    float e = __expf(fminf(x, 40.0f));
    float u = 1.0f + e;
    float u2 = u * u;
    return x * (u2 - 1.0f) * fast_rcp(u2 + 1.0f);
}
__device__ __forceinline__ float tanh_f(float y) {
    float e = __expf(2.0f * y);
    return 1.0f - 2.0f * fast_rcp(e + 1.0f);
}
__device__ __forceinline__ float sigmoid_f(float y) {
    return fast_rcp(1.0f + __expf(-y));
}
__device__ __forceinline__ float splus(float w) { return log1pf(__expf(w)); }

// ---------------- workspace layout (bytes) ----------------
#define WS_PERM      0u           // int[262144]
#define WS_GCOUNT    1048576u     // int[16]
#define WS_GSC       1048640u     // int[16]
#define WS_GOFF      1048704u     // int[16]
#define WS_BBAND     1048768u     // int[4112]
#define WS_BSTART    1065216u     // int[4112]
#define WS_BNROWS    1081664u     // int[4112]
#define WS_SP        1098112u     // float[32]
#define WS_W1P       1098240u     // u16[512*32]
#define WS_W2P       1131008u     // u16[256*512]
#define WS_HW1P      1393152u     // u16[9*128*256]
#define WS_SW1P      1982976u     // u16[64*256]
#define WS_STW1P     2015744u     // u16[64*256]
#define WS_NEEDED    2048512u

// ---------------- weight packing (+ zero counters, softplus tiny weights) ----------------
__global__ void k_pack(const float* __restrict__ tw1, const float* __restrict__ tw2,
                       const float* __restrict__ hw1,
                       const float* __restrict__ sw1, const float* __restrict__ stw1,
                       const float* __restrict__ sun_w1, const float* __restrict__ sun_w2,
                       const float* __restrict__ storm_w1, const float* __restrict__ storm_w2,
                       u16* __restrict__ W1p, u16* __restrict__ W2p, u16* __restrict__ HW1p,
                       u16* __restrict__ SW1p, u16* __restrict__ STW1p,
                       float* __restrict__ sp, int* __restrict__ gcount)
{
    int tid = blockIdx.x * blockDim.x + threadIdx.x;
    if (tid == 0) for (int i = 0; i < 16; ++i) gcount[i] = 0;
    if (tid < 32) {
        const float* srcs[4] = { sun_w1, sun_w2, storm_w1, storm_w2 };
        float w = srcs[tid >> 3][tid & 7];
        sp[tid] = splus(w);
    }
    const int total = 16384 + 131072 + 294912 + 16384 + 16384;
    for (int i = tid; i < total; i += gridDim.x * blockDim.x) {
        int idx = i;
        if (idx < 16384) {                         // W1p[n][k] : 512 x 32 (k>=15 zero)
            int n = idx >> 5, k = idx & 31;
            W1p[idx] = (k < 15) ? f2b(tw1[k * 512 + n]) : (u16)0;
        } else if ((idx -= 16384) < 131072) {      // W2p[n][k] : 256 x 512
            int n = idx >> 9, k = idx & 511;
            W2p[idx] = f2b(tw2[k * 256 + n]);
        } else if ((idx -= 131072) < 294912) {     // HW1p[g][h][d] : 9 x 128 x 256
            int g = idx >> 15, r = idx & 32767;
            int h = r >> 8, d = r & 255;
            HW1p[idx] = f2b(hw1[(g * 256 + d) * 128 + h]);
        } else if ((idx -= 294912) < 16384) {      // SW1p[n][d] : 64 x 256
            int n = idx >> 8, d = idx & 255;
            SW1p[idx] = f2b(sw1[d * 64 + n]);
        } else {                                   // STW1p[n][d]
            idx -= 16384;
            int n = idx >> 8, d = idx & 255;
            STW1p[idx] = f2b(stw1[d * 64 + n]);
        }
    }
}

// ---------------- band histogram ----------------
__global__ void k_hist(const float* __restrict__ x, int* __restrict__ gcount, int B) {
    __shared__ int h[9];
    int tid = threadIdx.x;
    if (tid < 9) h[tid] = 0;
    __syncthreads();
    for (int i = blockIdx.x * blockDim.x + tid; i < B; i += gridDim.x * blockDim.x) {
        int b = (int)x[i * 18 + 17];
        atomicAdd(&h[b], 1);
    }
    __syncthreads();
    if (tid < 9) atomicAdd(&gcount[tid], h[tid]);
}

// ---------------- group offsets + per-block table ----------------
__global__ void k_table(const int* __restrict__ gcount, int* __restrict__ goff,
                        int* __restrict__ gsc, int* __restrict__ blk_band,
                        int* __restrict__ blk_start, int* __restrict__ blk_nrows, int nblk_max)
{
    __shared__ int s_goff[10], s_bstart[10], s_cnt[9];
    int tid = threadIdx.x;
    if (tid == 0) {
        int off = 0, boff = 0;
        for (int g = 0; g < 9; ++g) {
            s_cnt[g] = gcount[g];
            s_goff[g] = off; goff[g] = off;
            s_bstart[g] = boff;
            off += s_cnt[g];
            boff += (s_cnt[g] + 63) >> 6;
        }
        s_goff[9] = off; goff[9] = off;
        s_bstart[9] = boff;
        for (int g = 0; g < 9; ++g) gsc[g] = 0;
    }
    __syncthreads();
    for (int b = tid; b < nblk_max; b += blockDim.x) {
        int band = -1, loc = 0;
        for (int g = 0; g < 9; ++g)
            if (b >= s_bstart[g] && b < s_bstart[g + 1]) { band = g; loc = b - s_bstart[g]; }
        blk_band[b] = band;
        if (band >= 0) {
            blk_start[b] = s_goff[band] + loc * 64;
            int rem = s_cnt[band] - loc * 64;
            blk_nrows[b] = rem < 64 ? rem : 64;
        } else { blk_start[b] = 0; blk_nrows[b] = 0; }
    }
}

// ---------------- counting-sort scatter: perm[grouped_pos] = original_row ----------------
__global__ void k_scatter(const float* __restrict__ x, const int* __restrict__ goff,
                          int* __restrict__ gsc, int* __restrict__ perm, int B)
{
    __shared__ int wcnt[4][9];
    __shared__ int wpre[4][9];
    __shared__ int gbase[9];
    int tid = threadIdx.x;
    int lane = tid & 63, wave = tid >> 6;
    int i = blockIdx.x * blockDim.x + tid;
    int band = -1, rank = 0;
    if (i < B) band = (int)x[i * 18 + 17];
    for (int k = 0; k < 9; ++k) {
        unsigned long long m = __ballot(band == k);
        if (band == k) rank = __popcll(m & ((1ull << lane) - 1ull));
        if (lane == 0) wcnt[wave][k] = __popcll(m);
    }
    __syncthreads();
    if (tid < 9) {
        int k = tid, run = 0;
        for (int w = 0; w < 4; ++w) { wpre[w][k] = run; run += wcnt[w][k]; }
        gbase[k] = (run > 0) ? atomicAdd(&gsc[k], run) : 0;
    }
    __syncthreads();
    if (i < B && band >= 0) {
        int pos = goff[band] + gbase[band] + wpre[wave][band] + rank;
        perm[pos] = i;
    }
}

// ---------------- fused main kernel: 64 rows / block, uniform band ----------------
__global__ void k_main(const float* __restrict__ x,
                       const int* __restrict__ perm,
                       const int* __restrict__ blk_band,
                       const int* __restrict__ blk_start,
                       const int* __restrict__ blk_nrows,
                       const u16* __restrict__ W1p, const u16* __restrict__ W2p,
                       const u16* __restrict__ HW1p,
                       const u16* __restrict__ SW1p, const u16* __restrict__ STW1p,
                       const float* __restrict__ tb1, const float* __restrict__ tb2,
                       const float* __restrict__ hb1, const float* __restrict__ hw2,
                       const float* __restrict__ hb2,
                       const float* __restrict__ sb1, const float* __restrict__ sw2,
                       const float* __restrict__ sb2,
                       const float* __restrict__ stb1, const float* __restrict__ stw2,
                       const float* __restrict__ stb2,
                       const float* __restrict__ sp,
                       const float* __restrict__ sun_b1, const float* __restrict__ sun_b2,
                       const float* __restrict__ storm_b1, const float* __restrict__ storm_b2,
                       float* __restrict__ out)
{
    int bb = blk_band[blockIdx.x];
    if (bb < 0) return;
    int rstart = blk_start[blockIdx.x];
    int nrows  = blk_nrows[blockIdx.x];

    __shared__ u16 xA[64][32];                 // bf16 x_deep, K padded to 32
    __shared__ int rowsL[64];
    __shared__ float sfiL[64], kpL[64];
    __shared__ u16 buf[2][64][136];            // P1 chunk double buffer; later aliased as t[64][264]
    __shared__ float headp[4][64], sunp[4][64], stormp[4][64];

    int tid = threadIdx.x;
    int lane = tid & 63, wave = tid >> 6;
    int quad = lane >> 4, l15 = lane & 15;

    if (tid < 64) {
        int r = rstart + (tid < nrows ? tid : 0);
        rowsL[tid] = perm[r];
    }
    for (int i = tid; i < 64 * 32; i += 256) ((u16*)xA)[i] = 0;
    __syncthreads();
    for (int i = tid; i < 64 * 18; i += 256) {
        int r = i / 18, c = i - r * 18;
        float v = x[rowsL[r] * 18 + c];
        if (c < 15) xA[r][c] = f2b(v);
        else if (c == 15) sfiL[r] = v;
        else if (c == 16) kpL[r] = v;
    }
    __syncthreads();

    // A-fragments of x (constant across chunks): A[m=l15+16mt][k=quad*8+j]
    bf16x8 ax[4];
#pragma unroll
    for (int mt = 0; mt < 4; ++mt)
        ax[mt] = *(const bf16x8*)&xA[mt * 16 + l15][quad * 8];

    f32x4 acc2[4][4] = {};   // [ntile][mtile] trunk-L2 accumulator (wave cols = wave*64..+64)

    for (int c = 0; c < 4; ++c) {
        // ---- Phase 1: a1 chunk = mish(x @ tw1 + tb1) cols [c*128, c*128+128)
        f32x4 acc1[2][4] = {};
#pragma unroll
        for (int nt = 0; nt < 2; ++nt) {
            int ncol = c * 128 + wave * 32 + nt * 16 + l15;
            bf16x8 bw = *(const bf16x8*)&W1p[ncol * 32 + quad * 8];
#pragma unroll
            for (int mt = 0; mt < 4; ++mt)
                acc1[nt][mt] = MFMA16(ax[mt], bw, acc1[nt][mt]);
        }
        u16 (*bufc)[136] = buf[c & 1];
#pragma unroll
        for (int nt = 0; nt < 2; ++nt) {
            int ccol = wave * 32 + nt * 16 + l15;
            float bias = tb1[c * 128 + ccol];
#pragma unroll
            for (int mt = 0; mt < 4; ++mt)
#pragma unroll
                for (int r = 0; r < 4; ++r)
                    bufc[mt * 16 + quad * 4 + r][ccol] = f2b(mish_f(acc1[nt][mt][r] + bias));
        }
        __syncthreads();
        // ---- Phase 2 partial: acc2 += chunk @ tw2[chunkK, wave cols]
        for (int ks = 0; ks < 4; ++ks) {
            bf16x8 a2[4];
#pragma unroll
            for (int mt = 0; mt < 4; ++mt)
                a2[mt] = *(const bf16x8*)&bufc[mt * 16 + l15][ks * 32 + quad * 8];
#pragma unroll
            for (int nt = 0; nt < 4; ++nt) {
                int n = wave * 64 + nt * 16 + l15;
                int k = c * 128 + ks * 32 + quad * 8;
                bf16x8 bw = *(const bf16x8*)&W2p[n * 512 + k];
#pragma unroll
                for (int mt = 0; mt < 4; ++mt)
                    acc2[nt][mt] = MFMA16(a2[mt], bw, acc2[nt][mt]);
            }
        }
    }
    __syncthreads();   // all P2 reads of buf done before aliasing it with t

    // ---- t = mish(acc2 + tb2) -> LDS t[64][264] (aliases buf)
    u16 (*tmat)[264] = (u16(*)[264])buf;
#pragma unroll
    for (int nt = 0; nt < 4; ++nt) {
        int col = wave * 64 + nt * 16 + l15;
        float bias = tb2[col];
#pragma unroll
        for (int mt = 0; mt < 4; ++mt)
#pragma unroll
            for (int r = 0; r < 4; ++r)
                tmat[mt * 16 + quad * 4 + r][col] = f2b(mish_f(acc2[nt][mt][r] + bias));
    }
    __syncthreads();

    // ---- Phase 3 unified: head (2 ntiles) + sun (1) + storm (1), K=256
    f32x4 acch[2][4] = {}, accs[4] = {}, acct[4] = {};
    const u16* Hw = HW1p + bb * (128 * 256);
    for (int ks = 0; ks < 8; ++ks) {
        int k = ks * 32 + quad * 8;
        bf16x8 a3[4];
#pragma unroll
        for (int mt = 0; mt < 4; ++mt)
            a3[mt] = *(const bf16x8*)&tmat[mt * 16 + l15][k];
#pragma unroll
        for (int nt = 0; nt < 2; ++nt) {
            int n = wave * 32 + nt * 16 + l15;
            bf16x8 bw = *(const bf16x8*)&Hw[n * 256 + k];
#pragma unroll
            for (int mt = 0; mt < 4; ++mt)
                acch[nt][mt] = MFMA16(a3[mt], bw, acch[nt][mt]);
        }
        {
            int n = wave * 16 + l15;
            bf16x8 bs = *(const bf16x8*)&SW1p[n * 256 + k];
            bf16x8 bt = *(const bf16x8*)&STW1p[n * 256 + k];
#pragma unroll
            for (int mt = 0; mt < 4; ++mt) {
                accs[mt] = MFMA16(a3[mt], bs, accs[mt]);
                acct[mt] = MFMA16(a3[mt], bt, acct[mt]);
            }
        }
    }

    // head epilogue: per-row dot of mish(hh) with hw2[band]
    float hsum[4][4] = {};
#pragma unroll
    for (int nt = 0; nt < 2; ++nt) {
        int col = wave * 32 + nt * 16 + l15;
        float hb = hb1[bb * 128 + col];
        float wv = hw2[bb * 128 + col];
#pragma unroll
        for (int mt = 0; mt < 4; ++mt)
#pragma unroll
            for (int r = 0; r < 4; ++r)
                hsum[mt][r] += mish_f(acch[nt][mt][r] + hb) * wv;
    }
#pragma unroll
    for (int off = 1; off < 16; off <<= 1)
#pragma unroll
        for (int mt = 0; mt < 4; ++mt)
#pragma unroll
            for (int r = 0; r < 4; ++r)
                hsum[mt][r] += __shfl_xor(hsum[mt][r], off, 64);
    if (l15 == 0)
#pragma unroll
        for (int mt = 0; mt < 4; ++mt)
#pragma unroll
            for (int r = 0; r < 4; ++r)
                headp[wave][mt * 16 + quad * 4 + r] = hsum[mt][r];

    // gate epilogues
    float ssum[4][4], tsum[4][4];
    {
        int n = wave * 16 + l15;
        float sbias = sb1[n], svw = sw2[n];
        float tbias = stb1[n], tvw = stw2[n];
#pragma unroll
        for (int mt = 0; mt < 4; ++mt)
#pragma unroll
            for (int r = 0; r < 4; ++r) {
                ssum[mt][r] = mish_f(accs[mt][r] + sbias) * svw;
                tsum[mt][r] = mish_f(acct[mt][r] + tbias) * tvw;
            }
    }
#pragma unroll
    for (int off = 1; off < 16; off <<= 1)
#pragma unroll
        for (int mt = 0; mt < 4; ++mt)
#pragma unroll
            for (int r = 0; r < 4; ++r) {
                ssum[mt][r] += __shfl_xor(ssum[mt][r], off, 64);
                tsum[mt][r] += __shfl_xor(tsum[mt][r], off, 64);
            }
    if (l15 == 0)
#pragma unroll
        for (int mt = 0; mt < 4; ++mt)
#pragma unroll
            for (int r = 0; r < 4; ++r) {
                int row = mt * 16 + quad * 4 + r;
                sunp[wave][row] = ssum[mt][r];
                stormp[wave][row] = tsum[mt][r];
            }
    __syncthreads();

    // ---- final scalar math per row (fp32 output!)
    if (tid < 64 && tid < nrows) {
        int row = tid;
        float head = headp[0][row] + headp[1][row] + headp[2][row] + headp[3][row] + hb2[bb];
        float sl = sunp[0][row] + sunp[1][row] + sunp[2][row] + sunp[3][row] + sb2[0];
        float tl = stormp[0][row] + stormp[1][row] + stormp[2][row] + stormp[3][row] + stb2[0];
        float sg = sigmoid_f(sl);
        float tg = sigmoid_f(tl);
        float v1 = sfiL[row], v2 = kpL[row];
        float sun_val = sun_b2[0], storm_val = storm_b2[0];
#pragma unroll
        for (int j = 0; j < 8; ++j) {
            sun_val   += tanh_f(v1 * sp[j]      + sun_b1[j])   * sp[8 + j];
            storm_val += tanh_f(v2 * sp[16 + j] + storm_b1[j]) * sp[24 + j];
        }
        out[rowsL[row]] = head + sg * sun_val + tg * storm_val;
    }
}

// ---------------- fallback: pure-VALU scalar kernel (used if ws too small) ----------------
__global__ __launch_bounds__(64) void k_simple(
    const float* __restrict__ x,
    const float* __restrict__ tw1, const float* __restrict__ tb1,
    const float* __restrict__ tw2, const float* __restrict__ tb2,
    const float* __restrict__ hw1, const float* __restrict__ hb1,
    const float* __restrict__ hw2, const float* __restrict__ hb2,
    const float* __restrict__ sw1, const float* __restrict__ sb1,
    const float* __restrict__ sw2, const float* __restrict__ sb2,
    const float* __restrict__ stw1, const float* __restrict__ stb1,
    const float* __restrict__ stw2, const float* __restrict__ stb2,
    const float* __restrict__ sun_w1, const float* __restrict__ sun_b1,
    const float* __restrict__ sun_w2, const float* __restrict__ sun_b2,
    const float* __restrict__ storm_w1, const float* __restrict__ storm_b1,
    const float* __restrict__ storm_w2, const float* __restrict__ storm_b2,
    float* __restrict__ out)
{
    __shared__ u16 t_lds[256 * 64];

    const int lane = threadIdx.x;
    const int r = blockIdx.x * 64 + lane;

    float xr[15];
#pragma unroll
    for (int k = 0; k < 15; ++k) xr[k] = x[r * 18 + k];
    const float sfi = x[r * 18 + 15];
    const float kp  = x[r * 18 + 16];
    const int band  = (int)x[r * 18 + 17];

    for (int tc = 0; tc < 4; ++tc) {
        float acc[64];
#pragma unroll
        for (int j = 0; j < 64; ++j) acc[j] = 0.0f;
        for (int n = 0; n < 512; ++n) {
            float p = tb1[n];
#pragma unroll
            for (int k = 0; k < 15; ++k) p += xr[k] * tw1[k * 512 + n];
            const float a1n = mish_f(p);
            const float* w2 = &tw2[n * 256 + tc * 64];
#pragma unroll
            for (int j = 0; j < 64; ++j) acc[j] += a1n * w2[j];
        }
#pragma unroll
        for (int j = 0; j < 64; ++j)
            t_lds[(tc * 64 + j) * 64 + lane] = f2b(mish_f(acc[j] + tb2[tc * 64 + j]));
    }
    __syncthreads();

    float head_val = 0.0f;
    for (int g = 0; g < 9; ++g) {
        float hs = 0.0f;
        for (int hc = 0; hc < 2; ++hc) {
            float pre[64];
#pragma unroll
            for (int j = 0; j < 64; ++j) pre[j] = 0.0f;
            for (int d = 0; d < 256; ++d) {
                const float td = b2f(t_lds[d * 64 + lane]);
                const float* wv = &hw1[g * 32768 + d * 128 + hc * 64];
#pragma unroll
                for (int j = 0; j < 64; ++j) pre[j] += td * wv[j];
            }
#pragma unroll
            for (int j = 0; j < 64; ++j) {
                const int h = hc * 64 + j;
                hs += mish_f(pre[j] + hb1[g * 128 + h]) * hw2[g * 128 + h];
            }
        }
        head_val += (band == g) ? (hs + hb2[g]) : 0.0f;
    }

    float pre_s[64], pre_t[64];
#pragma unroll
    for (int j = 0; j < 64; ++j) { pre_s[j] = 0.0f; pre_t[j] = 0.0f; }
    for (int d = 0; d < 256; ++d) {
        const float td = b2f(t_lds[d * 64 + lane]);
        const float* ws1 = &sw1[d * 64];
        const float* wt1 = &stw1[d * 64];
#pragma unroll
        for (int j = 0; j < 64; ++j) {
            pre_s[j] += td * ws1[j];
            pre_t[j] += td * wt1[j];
        }
    }
    float ls = sb2[0], lt = stb2[0];
#pragma unroll
    for (int j = 0; j < 64; ++j) {
        ls += mish_f(pre_s[j] + sb1[j]) * sw2[j];
        lt += mish_f(pre_t[j] + stb1[j]) * stw2[j];
    }
    const float sg = sigmoid_f(ls);
    const float tg = sigmoid_f(lt);

    float sun_val = sun_b2[0], storm_val = storm_b2[0];
#pragma unroll
    for (int j = 0; j < 8; ++j) {
        sun_val   += tanh_f(sfi * splus(sun_w1[j])  + sun_b1[j])   * splus(sun_w2[j]);
        storm_val += tanh_f(kp * splus(storm_w1[j]) + storm_b1[j]) * splus(storm_w2[j]);
    }

    out[r] = head_val + sg * sun_val + tg * storm_val;
}

extern "C" void kernel_launch(void* const* d_in, const int* in_sizes, int n_in,
                              void* d_out, int out_size, void* d_ws, size_t ws_size,
                              hipStream_t stream) {
    (void)n_in; (void)out_size;
    const float* x        = (const float*)d_in[0];
    const float* tw1      = (const float*)d_in[1];
    const float* tb1      = (const float*)d_in[2];
    const float* tw2      = (const float*)d_in[3];
    const float* tb2      = (const float*)d_in[4];
    const float* hw1      = (const float*)d_in[5];
    const float* hb1      = (const float*)d_in[6];
    const float* hw2      = (const float*)d_in[7];
    const float* hb2      = (const float*)d_in[8];
    const float* sw1      = (const float*)d_in[9];
    const float* sb1      = (const float*)d_in[10];
    const float* sw2      = (const float*)d_in[11];
    const float* sb2      = (const float*)d_in[12];
    const float* stw1     = (const float*)d_in[13];
    const float* stb1     = (const float*)d_in[14];
    const float* stw2     = (const float*)d_in[15];
    const float* stb2     = (const float*)d_in[16];
    const float* sun_w1   = (const float*)d_in[17];
    const float* sun_b1   = (const float*)d_in[18];
    const float* sun_w2   = (const float*)d_in[19];
    const float* sun_b2   = (const float*)d_in[20];
    const float* storm_w1 = (const float*)d_in[21];
    const float* storm_b1 = (const float*)d_in[22];
    const float* storm_w2 = (const float*)d_in[23];
    const float* storm_b2 = (const float*)d_in[24];

    const int B = in_sizes[0] / 18;

    if (ws_size < (size_t)WS_NEEDED) {
        // workspace too small for the MFMA path: scalar fallback
        k_simple<<<B / 64, 64, 0, stream>>>(x, tw1, tb1, tw2, tb2, hw1, hb1, hw2, hb2,
                                            sw1, sb1, sw2, sb2, stw1, stb1, stw2, stb2,
                                            sun_w1, sun_b1, sun_w2, sun_b2,
                                            storm_w1, storm_b1, storm_w2, storm_b2,
                                            (float*)d_out);
        return;
    }

    char* ws = (char*)d_ws;
    int*   perm      = (int*)(ws + WS_PERM);
    int*   gcount    = (int*)(ws + WS_GCOUNT);
    int*   gsc       = (int*)(ws + WS_GSC);
    int*   goff      = (int*)(ws + WS_GOFF);
    int*   blk_band  = (int*)(ws + WS_BBAND);
    int*   blk_start = (int*)(ws + WS_BSTART);
    int*   blk_nrows = (int*)(ws + WS_BNROWS);
    float* sp        = (float*)(ws + WS_SP);
    u16*   W1p       = (u16*)(ws + WS_W1P);
    u16*   W2p       = (u16*)(ws + WS_W2P);
    u16*   HW1p      = (u16*)(ws + WS_HW1P);
    u16*   SW1p      = (u16*)(ws + WS_SW1P);
    u16*   STW1p     = (u16*)(ws + WS_STW1P);

    int nblk = B / 64 + 16;

    k_pack<<<512, 256, 0, stream>>>(tw1, tw2, hw1, sw1, stw1,
                                    sun_w1, sun_w2, storm_w1, storm_w2,
                                    W1p, W2p, HW1p, SW1p, STW1p, sp, gcount);
    k_hist<<<256, 256, 0, stream>>>(x, gcount, B);
    k_table<<<1, 256, 0, stream>>>(gcount, goff, gsc, blk_band, blk_start, blk_nrows, nblk);
    k_scatter<<<(B + 255) / 256, 256, 0, stream>>>(x, goff, gsc, perm, B);
    k_main<<<nblk, 256, 0, stream>>>(x, perm, blk_band, blk_start, blk_nrows,
                                     W1p, W2p, HW1p, SW1p, STW1p,
                                     tb1, tb2, hb1, hw2, hb2,
                                     sb1, sw2, sb2, stb1, stw2, stb2,
                                     sp, sun_b1, sun_b2, storm_b1, storm_b2,
                                     (float*)d_out);
}

// Round 4
// 462.390 us; speedup vs baseline: 1.0285x; 1.0285x over previous
//
#include <hip/hip_runtime.h>
#include <cstdint>

typedef unsigned short u16;
typedef __attribute__((ext_vector_type(8))) __bf16 bf16x8;
typedef __attribute__((ext_vector_type(4))) float f32x4;

#define MFMA16(a, b, c) __builtin_amdgcn_mfma_f32_16x16x32_bf16((a), (b), (c), 0, 0, 0)

__device__ __forceinline__ u16 f2b(float f) {
    union { float f; unsigned u; } v; v.f = f;
    unsigned r = v.u + 0x7fffu + ((v.u >> 16) & 1u);
    return (u16)(r >> 16);
}
__device__ __forceinline__ float b2f(u16 h) {
    union { unsigned u; float f; } v; v.u = ((unsigned)h) << 16; return v.f;
}
__device__ __forceinline__ float fast_rcp(float x) { return __builtin_amdgcn_rcpf(x); }
// mish(x) = x * tanh(softplus(x)) = x * (u^2-1)/(u^2+1), u = 1+e^x
__device__ __forceinline__ float mish_f(float x) {
    float e = __expf(fminf(x, 40.0f));
    float u = 1.0f + e;
    float u2 = u * u;
    return x * (u2 - 1.0f) * fast_rcp(u2 + 1.0f);
}
__device__ __forceinline__ float tanh_f(float y) {
    float e = __expf(2.0f * y);
    return 1.0f - 2.0f * fast_rcp(e + 1.0f);
}
__device__ __forceinline__ float sigmoid_f(float y) {
    return fast_rcp(1.0f + __expf(-y));
}
__device__ __forceinline__ float splus(float w) { return log1pf(__expf(w)); }

// ---------------- workspace layout (bytes) ----------------
#define WS_PERM      0u           // int[262144]
#define WS_GSC       1048576u     // int[16]
#define WS_GOFF      1048640u     // int[16]
#define WS_BBAND     1048704u     // int[4112]
#define WS_BSTART    1065152u     // int[4112]
#define WS_BNROWS    1081600u     // int[4112]
#define WS_SP        1098048u     // float[32]
#define WS_GPART     1098176u     // int[512*9] per-block band partial counts
#define WS_W1P       1116608u     // u16[512*32]
#define WS_W2P       1149376u     // u16[256*512]
#define WS_HW1P      1411520u     // u16[9*128*256]
#define WS_SW1P      2001344u     // u16[64*256]
#define WS_STW1P     2034112u     // u16[64*256]
#define WS_NEEDED    2066880u

#define PACK_BLOCKS  512

// ---------------- weight packing + fused band histogram ----------------
// Histogram: each block WRITES its own partial counts (no init needed under
// 0xAA-poisoned ws); k_table sums them.
__global__ void k_pack(const float* __restrict__ x, int B,
                       const float* __restrict__ tw1, const float* __restrict__ tw2,
                       const float* __restrict__ hw1,
                       const float* __restrict__ sw1, const float* __restrict__ stw1,
                       const float* __restrict__ sun_w1, const float* __restrict__ sun_w2,
                       const float* __restrict__ storm_w1, const float* __restrict__ storm_w2,
                       u16* __restrict__ W1p, u16* __restrict__ W2p, u16* __restrict__ HW1p,
                       u16* __restrict__ SW1p, u16* __restrict__ STW1p,
                       float* __restrict__ sp, int* __restrict__ gpart)
{
    __shared__ int h[9];
    int ltid = threadIdx.x;
    int tid = blockIdx.x * blockDim.x + ltid;
    if (ltid < 9) h[ltid] = 0;
    __syncthreads();
    for (int i = tid; i < B; i += PACK_BLOCKS * 256) {
        int b = (int)x[i * 18 + 17];
        atomicAdd(&h[b], 1);
    }

    if (tid < 32) {
        const float* srcs[4] = { sun_w1, sun_w2, storm_w1, storm_w2 };
        float w = srcs[tid >> 3][tid & 7];
        sp[tid] = splus(w);
    }
    const int total = 16384 + 131072 + 294912 + 16384 + 16384;
    for (int i = tid; i < total; i += PACK_BLOCKS * 256) {
        int idx = i;
        if (idx < 16384) {                         // W1p[n][k] : 512 x 32 (k>=15 zero)
            int n = idx >> 5, k = idx & 31;
            W1p[idx] = (k < 15) ? f2b(tw1[k * 512 + n]) : (u16)0;
        } else if ((idx -= 16384) < 131072) {      // W2p[n][k] : 256 x 512
            int n = idx >> 9, k = idx & 511;
            W2p[idx] = f2b(tw2[k * 256 + n]);
        } else if ((idx -= 131072) < 294912) {     // HW1p[g][h][d] : 9 x 128 x 256
            int g = idx >> 15, r = idx & 32767;
            int h2 = r >> 8, d = r & 255;
            HW1p[idx] = f2b(hw1[(g * 256 + d) * 128 + h2]);
        } else if ((idx -= 294912) < 16384) {      // SW1p[n][d] : 64 x 256
            int n = idx >> 8, d = idx & 255;
            SW1p[idx] = f2b(sw1[d * 64 + n]);
        } else {                                   // STW1p[n][d]
            idx -= 16384;
            int n = idx >> 8, d = idx & 255;
            STW1p[idx] = f2b(stw1[d * 64 + n]);
        }
    }
    __syncthreads();
    if (ltid < 9) gpart[blockIdx.x * 9 + ltid] = h[ltid];
}

// ---------------- sum partials, group offsets + per-block table ----------------
__global__ void k_table(const int* __restrict__ gpart, int* __restrict__ goff,
                        int* __restrict__ gsc, int* __restrict__ blk_band,
                        int* __restrict__ blk_start, int* __restrict__ blk_nrows, int nblk_max)
{
    __shared__ int s_goff[10], s_bstart[10], s_cnt[9];
    int tid = threadIdx.x;
    if (tid < 9) {
        int s = 0;
        for (int b = 0; b < PACK_BLOCKS; ++b) s += gpart[b * 9 + tid];
        s_cnt[tid] = s;
    }
    __syncthreads();
    if (tid == 0) {
        int off = 0, boff = 0;
        for (int g = 0; g < 9; ++g) {
            s_goff[g] = off; goff[g] = off;
            s_bstart[g] = boff;
            off += s_cnt[g];
            boff += (s_cnt[g] + 63) >> 6;
        }
        s_goff[9] = off; goff[9] = off;
        s_bstart[9] = boff;
        for (int g = 0; g < 9; ++g) gsc[g] = 0;
    }
    __syncthreads();
    for (int b = tid; b < nblk_max; b += blockDim.x) {
        int band = -1, loc = 0;
        for (int g = 0; g < 9; ++g)
            if (b >= s_bstart[g] && b < s_bstart[g + 1]) { band = g; loc = b - s_bstart[g]; }
        blk_band[b] = band;
        if (band >= 0) {
            blk_start[b] = s_goff[band] + loc * 64;
            int rem = s_cnt[band] - loc * 64;
            blk_nrows[b] = rem < 64 ? rem : 64;
        } else { blk_start[b] = 0; blk_nrows[b] = 0; }
    }
}

// ---------------- counting-sort scatter: perm[grouped_pos] = original_row ----------------
__global__ void k_scatter(const float* __restrict__ x, const int* __restrict__ goff,
                          int* __restrict__ gsc, int* __restrict__ perm, int B)
{
    __shared__ int wcnt[4][9];
    __shared__ int wpre[4][9];
    __shared__ int gbase[9];
    int tid = threadIdx.x;
    int lane = tid & 63, wave = tid >> 6;
    int i = blockIdx.x * blockDim.x + tid;
    int band = -1, rank = 0;
    if (i < B) band = (int)x[i * 18 + 17];
    for (int k = 0; k < 9; ++k) {
        unsigned long long m = __ballot(band == k);
        if (band == k) rank = __popcll(m & ((1ull << lane) - 1ull));
        if (lane == 0) wcnt[wave][k] = __popcll(m);
    }
    __syncthreads();
    if (tid < 9) {
        int k = tid, run = 0;
        for (int w = 0; w < 4; ++w) { wpre[w][k] = run; run += wcnt[w][k]; }
        gbase[k] = (run > 0) ? atomicAdd(&gsc[k], run) : 0;
    }
    __syncthreads();
    if (i < B && band >= 0) {
        int pos = goff[band] + gbase[band] + wpre[wave][band] + rank;
        perm[pos] = i;
    }
}

// ---------------- fused main kernel: 64 rows / block, uniform band ----------------
// __launch_bounds__(256): without it the compiler assumes 1024-thread blocks
// and caps VGPRs at 64 -> massive scratch spill (round-3 rocprof: 170 MB
// WRITE_SIZE/dispatch of pure spill traffic).
__global__ __launch_bounds__(256) void k_main(
                       const float* __restrict__ x,
                       const int* __restrict__ perm,
                       const int* __restrict__ blk_band,
                       const int* __restrict__ blk_start,
                       const int* __restrict__ blk_nrows,
                       const u16* __restrict__ W1p, const u16* __restrict__ W2p,
                       const u16* __restrict__ HW1p,
                       const u16* __restrict__ SW1p, const u16* __restrict__ STW1p,
                       const float* __restrict__ tb1, const float* __restrict__ tb2,
                       const float* __restrict__ hb1, const float* __restrict__ hw2,
                       const float* __restrict__ hb2,
                       const float* __restrict__ sb1, const float* __restrict__ sw2,
                       const float* __restrict__ sb2,
                       const float* __restrict__ stb1, const float* __restrict__ stw2,
                       const float* __restrict__ stb2,
                       const float* __restrict__ sp,
                       const float* __restrict__ sun_b1, const float* __restrict__ sun_b2,
                       const float* __restrict__ storm_b1, const float* __restrict__ storm_b2,
                       float* __restrict__ out)
{
    int bb = blk_band[blockIdx.x];
    if (bb < 0) return;
    int rstart = blk_start[blockIdx.x];
    int nrows  = blk_nrows[blockIdx.x];

    __shared__ u16 xA[64][32];                 // bf16 x_deep, K padded to 32
    __shared__ int rowsL[64];
    __shared__ float sfiL[64], kpL[64];
    __shared__ u16 buf[2][64][136];            // P1 chunk double buffer; later aliased as t[64][264]
    __shared__ float headp[4][64], sunp[4][64], stormp[4][64];

    int tid = threadIdx.x;
    int lane = tid & 63, wave = tid >> 6;
    int quad = lane >> 4, l15 = lane & 15;

    if (tid < 64) {
        int r = rstart + (tid < nrows ? tid : 0);
        rowsL[tid] = perm[r];
    }
    for (int i = tid; i < 64 * 32; i += 256) ((u16*)xA)[i] = 0;
    __syncthreads();
    for (int i = tid; i < 64 * 18; i += 256) {
        int r = i / 18, c = i - r * 18;
        float v = x[rowsL[r] * 18 + c];
        if (c < 15) xA[r][c] = f2b(v);
        else if (c == 15) sfiL[r] = v;
        else if (c == 16) kpL[r] = v;
    }
    __syncthreads();

    // A-fragments of x (constant across chunks): A[m=l15+16mt][k=quad*8+j]
    bf16x8 ax[4];
#pragma unroll
    for (int mt = 0; mt < 4; ++mt)
        ax[mt] = *(const bf16x8*)&xA[mt * 16 + l15][quad * 8];

    f32x4 acc2[4][4] = {};   // [ntile][mtile] trunk-L2 accumulator (wave cols = wave*64..+64)

    for (int c = 0; c < 4; ++c) {
        // ---- Phase 1: a1 chunk = mish(x @ tw1 + tb1) cols [c*128, c*128+128)
        f32x4 acc1[2][4] = {};
#pragma unroll
        for (int nt = 0; nt < 2; ++nt) {
            int ncol = c * 128 + wave * 32 + nt * 16 + l15;
            bf16x8 bw = *(const bf16x8*)&W1p[ncol * 32 + quad * 8];
#pragma unroll
            for (int mt = 0; mt < 4; ++mt)
                acc1[nt][mt] = MFMA16(ax[mt], bw, acc1[nt][mt]);
        }
        u16 (*bufc)[136] = buf[c & 1];
#pragma unroll
        for (int nt = 0; nt < 2; ++nt) {
            int ccol = wave * 32 + nt * 16 + l15;
            float bias = tb1[c * 128 + ccol];
#pragma unroll
            for (int mt = 0; mt < 4; ++mt)
#pragma unroll
                for (int r = 0; r < 4; ++r)
                    bufc[mt * 16 + quad * 4 + r][ccol] = f2b(mish_f(acc1[nt][mt][r] + bias));
        }
        __syncthreads();
        // ---- Phase 2 partial: acc2 += chunk @ tw2[chunkK, wave cols]
        for (int ks = 0; ks < 4; ++ks) {
            bf16x8 a2[4];
#pragma unroll
            for (int mt = 0; mt < 4; ++mt)
                a2[mt] = *(const bf16x8*)&bufc[mt * 16 + l15][ks * 32 + quad * 8];
#pragma unroll
            for (int nt = 0; nt < 4; ++nt) {
                int n = wave * 64 + nt * 16 + l15;
                int k = c * 128 + ks * 32 + quad * 8;
                bf16x8 bw = *(const bf16x8*)&W2p[n * 512 + k];
#pragma unroll
                for (int mt = 0; mt < 4; ++mt)
                    acc2[nt][mt] = MFMA16(a2[mt], bw, acc2[nt][mt]);
            }
        }
    }
    __syncthreads();   // all P2 reads of buf done before aliasing it with t

    // ---- t = mish(acc2 + tb2) -> LDS t[64][264] (aliases buf)
    u16 (*tmat)[264] = (u16(*)[264])buf;
#pragma unroll
    for (int nt = 0; nt < 4; ++nt) {
        int col = wave * 64 + nt * 16 + l15;
        float bias = tb2[col];
#pragma unroll
        for (int mt = 0; mt < 4; ++mt)
#pragma unroll
            for (int r = 0; r < 4; ++r)
                tmat[mt * 16 + quad * 4 + r][col] = f2b(mish_f(acc2[nt][mt][r] + bias));
    }
    __syncthreads();

    // ---- Phase 3 unified: head (2 ntiles) + sun (1) + storm (1), K=256
    f32x4 acch[2][4] = {}, accs[4] = {}, acct[4] = {};
    const u16* Hw = HW1p + bb * (128 * 256);
    for (int ks = 0; ks < 8; ++ks) {
        int k = ks * 32 + quad * 8;
        bf16x8 a3[4];
#pragma unroll
        for (int mt = 0; mt < 4; ++mt)
            a3[mt] = *(const bf16x8*)&tmat[mt * 16 + l15][k];
#pragma unroll
        for (int nt = 0; nt < 2; ++nt) {
            int n = wave * 32 + nt * 16 + l15;
            bf16x8 bw = *(const bf16x8*)&Hw[n * 256 + k];
#pragma unroll
            for (int mt = 0; mt < 4; ++mt)
                acch[nt][mt] = MFMA16(a3[mt], bw, acch[nt][mt]);
        }
        {
            int n = wave * 16 + l15;
            bf16x8 bs = *(const bf16x8*)&SW1p[n * 256 + k];
            bf16x8 bt = *(const bf16x8*)&STW1p[n * 256 + k];
#pragma unroll
            for (int mt = 0; mt < 4; ++mt) {
                accs[mt] = MFMA16(a3[mt], bs, accs[mt]);
                acct[mt] = MFMA16(a3[mt], bt, acct[mt]);
            }
        }
    }

    // head epilogue: per-row dot of mish(hh) with hw2[band]
    float hsum[4][4] = {};
#pragma unroll
    for (int nt = 0; nt < 2; ++nt) {
        int col = wave * 32 + nt * 16 + l15;
        float hb = hb1[bb * 128 + col];
        float wv = hw2[bb * 128 + col];
#pragma unroll
        for (int mt = 0; mt < 4; ++mt)
#pragma unroll
            for (int r = 0; r < 4; ++r)
                hsum[mt][r] += mish_f(acch[nt][mt][r] + hb) * wv;
    }
#pragma unroll
    for (int off = 1; off < 16; off <<= 1)
#pragma unroll
        for (int mt = 0; mt < 4; ++mt)
#pragma unroll
            for (int r = 0; r < 4; ++r)
                hsum[mt][r] += __shfl_xor(hsum[mt][r], off, 64);
    if (l15 == 0)
#pragma unroll
        for (int mt = 0; mt < 4; ++mt)
#pragma unroll
            for (int r = 0; r < 4; ++r)
                headp[wave][mt * 16 + quad * 4 + r] = hsum[mt][r];

    // gate epilogues
    float ssum[4][4], tsum[4][4];
    {
        int n = wave * 16 + l15;
        float sbias = sb1[n], svw = sw2[n];
        float tbias = stb1[n], tvw = stw2[n];
#pragma unroll
        for (int mt = 0; mt < 4; ++mt)
#pragma unroll
            for (int r = 0; r < 4; ++r) {
                ssum[mt][r] = mish_f(accs[mt][r] + sbias) * svw;
                tsum[mt][r] = mish_f(acct[mt][r] + tbias) * tvw;
            }
    }
#pragma unroll
    for (int off = 1; off < 16; off <<= 1)
#pragma unroll
        for (int mt = 0; mt < 4; ++mt)
#pragma unroll
            for (int r = 0; r < 4; ++r) {
                ssum[mt][r] += __shfl_xor(ssum[mt][r], off, 64);
                tsum[mt][r] += __shfl_xor(tsum[mt][r], off, 64);
            }
    if (l15 == 0)
#pragma unroll
        for (int mt = 0; mt < 4; ++mt)
#pragma unroll
            for (int r = 0; r < 4; ++r) {
                int row = mt * 16 + quad * 4 + r;
                sunp[wave][row] = ssum[mt][r];
                stormp[wave][row] = tsum[mt][r];
            }
    __syncthreads();

    // ---- final scalar math per row (fp32 output)
    if (tid < 64 && tid < nrows) {
        int row = tid;
        float head = headp[0][row] + headp[1][row] + headp[2][row] + headp[3][row] + hb2[bb];
        float sl = sunp[0][row] + sunp[1][row] + sunp[2][row] + sunp[3][row] + sb2[0];
        float tl = stormp[0][row] + stormp[1][row] + stormp[2][row] + stormp[3][row] + stb2[0];
        float sg = sigmoid_f(sl);
        float tg = sigmoid_f(tl);
        float v1 = sfiL[row], v2 = kpL[row];
        float sun_val = sun_b2[0], storm_val = storm_b2[0];
#pragma unroll
        for (int j = 0; j < 8; ++j) {
            sun_val   += tanh_f(v1 * sp[j]      + sun_b1[j])   * sp[8 + j];
            storm_val += tanh_f(v2 * sp[16 + j] + storm_b1[j]) * sp[24 + j];
        }
        out[rowsL[row]] = head + sg * sun_val + tg * storm_val;
    }
}

// ---------------- fallback: pure-VALU scalar kernel (used if ws too small) ----------------
__global__ __launch_bounds__(64) void k_simple(
    const float* __restrict__ x,
    const float* __restrict__ tw1, const float* __restrict__ tb1,
    const float* __restrict__ tw2, const float* __restrict__ tb2,
    const float* __restrict__ hw1, const float* __restrict__ hb1,
    const float* __restrict__ hw2, const float* __restrict__ hb2,
    const float* __restrict__ sw1, const float* __restrict__ sb1,
    const float* __restrict__ sw2, const float* __restrict__ sb2,
    const float* __restrict__ stw1, const float* __restrict__ stb1,
    const float* __restrict__ stw2, const float* __restrict__ stb2,
    const float* __restrict__ sun_w1, const float* __restrict__ sun_b1,
    const float* __restrict__ sun_w2, const float* __restrict__ sun_b2,
    const float* __restrict__ storm_w1, const float* __restrict__ storm_b1,
    const float* __restrict__ storm_w2, const float* __restrict__ storm_b2,
    float* __restrict__ out)
{
    __shared__ u16 t_lds[256 * 64];

    const int lane = threadIdx.x;
    const int r = blockIdx.x * 64 + lane;

    float xr[15];
#pragma unroll
    for (int k = 0; k < 15; ++k) xr[k] = x[r * 18 + k];
    const float sfi = x[r * 18 + 15];
    const float kp  = x[r * 18 + 16];
    const int band  = (int)x[r * 18 + 17];

    for (int tc = 0; tc < 4; ++tc) {
        float acc[64];
#pragma unroll
        for (int j = 0; j < 64; ++j) acc[j] = 0.0f;
        for (int n = 0; n < 512; ++n) {
            float p = tb1[n];
#pragma unroll
            for (int k = 0; k < 15; ++k) p += xr[k] * tw1[k * 512 + n];
            const float a1n = mish_f(p);
            const float* w2 = &tw2[n * 256 + tc * 64];
#pragma unroll
            for (int j = 0; j < 64; ++j) acc[j] += a1n * w2[j];
        }
#pragma unroll
        for (int j = 0; j < 64; ++j)
            t_lds[(tc * 64 + j) * 64 + lane] = f2b(mish_f(acc[j] + tb2[tc * 64 + j]));
    }
    __syncthreads();

    float head_val = 0.0f;
    for (int g = 0; g < 9; ++g) {
        float hs = 0.0f;
        for (int hc = 0; hc < 2; ++hc) {
            float pre[64];
#pragma unroll
            for (int j = 0; j < 64; ++j) pre[j] = 0.0f;
            for (int d = 0; d < 256; ++d) {
                const float td = b2f(t_lds[d * 64 + lane]);
                const float* wv = &hw1[g * 32768 + d * 128 + hc * 64];
#pragma unroll
                for (int j = 0; j < 64; ++j) pre[j] += td * wv[j];
            }
#pragma unroll
            for (int j = 0; j < 64; ++j) {
                const int h = hc * 64 + j;
                hs += mish_f(pre[j] + hb1[g * 128 + h]) * hw2[g * 128 + h];
            }
        }
        head_val += (band == g) ? (hs + hb2[g]) : 0.0f;
    }

    float pre_s[64], pre_t[64];
#pragma unroll
    for (int j = 0; j < 64; ++j) { pre_s[j] = 0.0f; pre_t[j] = 0.0f; }
    for (int d = 0; d < 256; ++d) {
        const float td = b2f(t_lds[d * 64 + lane]);
        const float* ws1 = &sw1[d * 64];
        const float* wt1 = &stw1[d * 64];
#pragma unroll
        for (int j = 0; j < 64; ++j) {
            pre_s[j] += td * ws1[j];
            pre_t[j] += td * wt1[j];
        }
    }
    float ls = sb2[0], lt = stb2[0];
#pragma unroll
    for (int j = 0; j < 64; ++j) {
        ls += mish_f(pre_s[j] + sb1[j]) * sw2[j];
        lt += mish_f(pre_t[j] + stb1[j]) * stw2[j];
    }
    const float sg = sigmoid_f(ls);
    const float tg = sigmoid_f(lt);

    float sun_val = sun_b2[0], storm_val = storm_b2[0];
#pragma unroll
    for (int j = 0; j < 8; ++j) {
        sun_val   += tanh_f(sfi * splus(sun_w1[j])  + sun_b1[j])   * splus(sun_w2[j]);
        storm_val += tanh_f(kp * splus(storm_w1[j]) + storm_b1[j]) * splus(storm_w2[j]);
    }

    out[r] = head_val + sg * sun_val + tg * storm_val;
}

extern "C" void kernel_launch(void* const* d_in, const int* in_sizes, int n_in,
                              void* d_out, int out_size, void* d_ws, size_t ws_size,
                              hipStream_t stream) {
    (void)n_in; (void)out_size;
    const float* x        = (const float*)d_in[0];
    const float* tw1      = (const float*)d_in[1];
    const float* tb1      = (const float*)d_in[2];
    const float* tw2      = (const float*)d_in[3];
    const float* tb2      = (const float*)d_in[4];
    const float* hw1      = (const float*)d_in[5];
    const float* hb1      = (const float*)d_in[6];
    const float* hw2      = (const float*)d_in[7];
    const float* hb2      = (const float*)d_in[8];
    const float* sw1      = (const float*)d_in[9];
    const float* sb1      = (const float*)d_in[10];
    const float* sw2      = (const float*)d_in[11];
    const float* sb2      = (const float*)d_in[12];
    const float* stw1     = (const float*)d_in[13];
    const float* stb1     = (const float*)d_in[14];
    const float* stw2     = (const float*)d_in[15];
    const float* stb2     = (const float*)d_in[16];
    const float* sun_w1   = (const float*)d_in[17];
    const float* sun_b1   = (const float*)d_in[18];
    const float* sun_w2   = (const float*)d_in[19];
    const float* sun_b2   = (const float*)d_in[20];
    const float* storm_w1 = (const float*)d_in[21];
    const float* storm_b1 = (const float*)d_in[22];
    const float* storm_w2 = (const float*)d_in[23];
    const float* storm_b2 = (const float*)d_in[24];

    const int B = in_sizes[0] / 18;

    if (ws_size < (size_t)WS_NEEDED) {
        k_simple<<<B / 64, 64, 0, stream>>>(x, tw1, tb1, tw2, tb2, hw1, hb1, hw2, hb2,
                                            sw1, sb1, sw2, sb2, stw1, stb1, stw2, stb2,
                                            sun_w1, sun_b1, sun_w2, sun_b2,
                                            storm_w1, storm_b1, storm_w2, storm_b2,
                                            (float*)d_out);
        return;
    }

    char* ws = (char*)d_ws;
    int*   perm      = (int*)(ws + WS_PERM);
    int*   gsc       = (int*)(ws + WS_GSC);
    int*   goff      = (int*)(ws + WS_GOFF);
    int*   blk_band  = (int*)(ws + WS_BBAND);
    int*   blk_start = (int*)(ws + WS_BSTART);
    int*   blk_nrows = (int*)(ws + WS_BNROWS);
    float* sp        = (float*)(ws + WS_SP);
    int*   gpart     = (int*)(ws + WS_GPART);
    u16*   W1p       = (u16*)(ws + WS_W1P);
    u16*   W2p       = (u16*)(ws + WS_W2P);
    u16*   HW1p      = (u16*)(ws + WS_HW1P);
    u16*   SW1p      = (u16*)(ws + WS_SW1P);
    u16*   STW1p     = (u16*)(ws + WS_STW1P);

    int nblk = B / 64 + 16;

    k_pack<<<PACK_BLOCKS, 256, 0, stream>>>(x, B, tw1, tw2, hw1, sw1, stw1,
                                            sun_w1, sun_w2, storm_w1, storm_w2,
                                            W1p, W2p, HW1p, SW1p, STW1p, sp, gpart);
    k_table<<<1, 256, 0, stream>>>(gpart, goff, gsc, blk_band, blk_start, blk_nrows, nblk);
    k_scatter<<<(B + 255) / 256, 256, 0, stream>>>(x, goff, gsc, perm, B);
    k_main<<<nblk, 256, 0, stream>>>(x, perm, blk_band, blk_start, blk_nrows,
                                     W1p, W2p, HW1p, SW1p, STW1p,
                                     tb1, tb2, hb1, hw2, hb2,
                                     sb1, sw2, sb2, stb1, stw2, stb2,
                                     sp, sun_b1, sun_b2, storm_b1, storm_b2,
                                     (float*)d_out);
}

// Round 5
// 334.038 us; speedup vs baseline: 1.4237x; 1.3842x over previous
//
#include <hip/hip_runtime.h>
#include <cstdint>

typedef unsigned short u16;
typedef __attribute__((ext_vector_type(8))) __bf16 bf16x8;
typedef __attribute__((ext_vector_type(4))) float f32x4;

#define MFMA16(a, b, c) __builtin_amdgcn_mfma_f32_16x16x32_bf16((a), (b), (c), 0, 0, 0)

__device__ __forceinline__ u16 f2b(float f) {
    union { float f; unsigned u; } v; v.f = f;
    unsigned r = v.u + 0x7fffu + ((v.u >> 16) & 1u);
    return (u16)(r >> 16);
}
__device__ __forceinline__ float b2f(u16 h) {
    union { unsigned u; float f; } v; v.u = ((unsigned)h) << 16; return v.f;
}
__device__ __forceinline__ float fast_rcp(float x) { return __builtin_amdgcn_rcpf(x); }
// mish(x) = x * tanh(softplus(x)) = x * (u^2-1)/(u^2+1), u = 1+e^x
__device__ __forceinline__ float mish_f(float x) {
    float e = __expf(fminf(x, 40.0f));
    float u = 1.0f + e;
    float u2 = u * u;
    return x * (u2 - 1.0f) * fast_rcp(u2 + 1.0f);
}
__device__ __forceinline__ float tanh_f(float y) {
    float e = __expf(2.0f * y);
    return 1.0f - 2.0f * fast_rcp(e + 1.0f);
}
__device__ __forceinline__ float sigmoid_f(float y) {
    return fast_rcp(1.0f + __expf(-y));
}
__device__ __forceinline__ float splus(float w) { return log1pf(__expf(w)); }

// ---------------- workspace layout (bytes) ----------------
#define WS_PERM      0u           // int[262144]
#define WS_GSC       1048576u     // int[16]
#define WS_GOFF      1048640u     // int[16]
#define WS_BBAND     1048704u     // int[4112]
#define WS_BSTART    1065152u     // int[4112]
#define WS_BNROWS    1081600u     // int[4112]
#define WS_SP        1098048u     // float[32]
#define WS_GPART     1098176u     // int[512*9]
#define WS_W1P       1116608u     // u16[512*32]   [n][k] (coalesced: K=32 -> 1KB/ntile)
#define WS_W2F       1149376u     // u16[256*512]  fragment-major, NT=16 KB=16
#define WS_HW1F      1411520u     // u16[9*128*256] fragment-major per band, NT=8 KB=8
#define WS_SWF       2001344u     // u16[64*256]   fragment-major, NT=4 KB=8
#define WS_STWF      2034112u     // u16[64*256]
#define WS_NEEDED    2066880u

#define PACK_BLOCKS  512

// Fragment-major (FM) layout: for tile (nt,kb), the 1KB block
//   FMbase + ((nt*KB + kb)*64 + lane)*8  (u16 units: *8 = 8 bf16 per lane)
// holds exactly the wave's B-fragment: lane=(quad*16+l15) -> W[nt*16+l15][kb*32+quad*8+j].
// One wave load = one contiguous 1KB transaction (round-4 fix: [n][k] layout put
// consecutive lanes 1KB apart -> 16 half-used cachelines per load, L2-latency-bound).

// ---------------- weight packing + fused band histogram ----------------
__global__ void k_pack(const float* __restrict__ x, int B,
                       const float* __restrict__ tw1, const float* __restrict__ tw2,
                       const float* __restrict__ hw1,
                       const float* __restrict__ sw1, const float* __restrict__ stw1,
                       const float* __restrict__ sun_w1, const float* __restrict__ sun_w2,
                       const float* __restrict__ storm_w1, const float* __restrict__ storm_w2,
                       u16* __restrict__ W1p, u16* __restrict__ W2f, u16* __restrict__ HWf,
                       u16* __restrict__ SWf, u16* __restrict__ STWf,
                       float* __restrict__ sp, int* __restrict__ gpart)
{
    __shared__ int h[9];
    int ltid = threadIdx.x;
    int tid = blockIdx.x * blockDim.x + ltid;
    if (ltid < 9) h[ltid] = 0;
    __syncthreads();
    for (int i = tid; i < B; i += PACK_BLOCKS * 256) {
        int b = (int)x[i * 18 + 17];
        atomicAdd(&h[b], 1);
    }

    if (tid < 32) {
        const float* srcs[4] = { sun_w1, sun_w2, storm_w1, storm_w2 };
        float w = srcs[tid >> 3][tid & 7];
        sp[tid] = splus(w);
    }
    const int total = 16384 + 131072 + 294912 + 16384 + 16384;
    for (int i = tid; i < total; i += PACK_BLOCKS * 256) {
        int idx = i;
        if (idx < 16384) {                         // W1p[n][k] : 512 x 32 (k>=15 zero)
            int n = idx >> 5, k = idx & 31;
            W1p[idx] = (k < 15) ? f2b(tw1[k * 512 + n]) : (u16)0;
        } else if ((idx -= 16384) < 131072) {      // W2f: FM, NT=16, KB=16
            int tile = idx >> 9, within = idx & 511;
            int lane = within >> 3, j = within & 7;
            int nt = tile >> 4, kb = tile & 15;
            int n = nt * 16 + (lane & 15);
            int k = kb * 32 + (lane >> 4) * 8 + j;
            W2f[idx] = f2b(tw2[k * 256 + n]);
        } else if ((idx -= 131072) < 294912) {     // HWf: per band g, FM NT=8, KB=8
            int g = idx >> 15, r = idx & 32767;
            int tile = r >> 9, within = r & 511;
            int lane = within >> 3, j = within & 7;
            int nt = tile >> 3, kb = tile & 7;
            int n = nt * 16 + (lane & 15);
            int k = kb * 32 + (lane >> 4) * 8 + j;
            HWf[idx] = f2b(hw1[(g * 256 + k) * 128 + n]);
        } else if ((idx -= 294912) < 16384) {      // SWf: FM NT=4, KB=8
            int tile = idx >> 9, within = idx & 511;
            int lane = within >> 3, j = within & 7;
            int nt = tile >> 3, kb = tile & 7;
            int n = nt * 16 + (lane & 15);
            int k = kb * 32 + (lane >> 4) * 8 + j;
            SWf[idx] = f2b(sw1[k * 64 + n]);
        } else {                                   // STWf
            idx -= 16384;
            int tile = idx >> 9, within = idx & 511;
            int lane = within >> 3, j = within & 7;
            int nt = tile >> 3, kb = tile & 7;
            int n = nt * 16 + (lane & 15);
            int k = kb * 32 + (lane >> 4) * 8 + j;
            STWf[idx] = f2b(stw1[k * 64 + n]);
        }
    }
    __syncthreads();
    if (ltid < 9) gpart[blockIdx.x * 9 + ltid] = h[ltid];
}

// ---------------- sum partials, group offsets + per-block table ----------------
__global__ void k_table(const int* __restrict__ gpart, int* __restrict__ goff,
                        int* __restrict__ gsc, int* __restrict__ blk_band,
                        int* __restrict__ blk_start, int* __restrict__ blk_nrows, int nblk_max)
{
    __shared__ int s_goff[10], s_bstart[10], s_cnt[9];
    int tid = threadIdx.x;
    if (tid < 9) {
        int s = 0;
        for (int b = 0; b < PACK_BLOCKS; ++b) s += gpart[b * 9 + tid];
        s_cnt[tid] = s;
    }
    __syncthreads();
    if (tid == 0) {
        int off = 0, boff = 0;
        for (int g = 0; g < 9; ++g) {
            s_goff[g] = off; goff[g] = off;
            s_bstart[g] = boff;
            off += s_cnt[g];
            boff += (s_cnt[g] + 63) >> 6;
        }
        s_goff[9] = off; goff[9] = off;
        s_bstart[9] = boff;
        for (int g = 0; g < 9; ++g) gsc[g] = 0;
    }
    __syncthreads();
    for (int b = tid; b < nblk_max; b += blockDim.x) {
        int band = -1, loc = 0;
        for (int g = 0; g < 9; ++g)
            if (b >= s_bstart[g] && b < s_bstart[g + 1]) { band = g; loc = b - s_bstart[g]; }
        blk_band[b] = band;
        if (band >= 0) {
            blk_start[b] = s_goff[band] + loc * 64;
            int rem = s_cnt[band] - loc * 64;
            blk_nrows[b] = rem < 64 ? rem : 64;
        } else { blk_start[b] = 0; blk_nrows[b] = 0; }
    }
}

// ---------------- counting-sort scatter ----------------
__global__ void k_scatter(const float* __restrict__ x, const int* __restrict__ goff,
                          int* __restrict__ gsc, int* __restrict__ perm, int B)
{
    __shared__ int wcnt[4][9];
    __shared__ int wpre[4][9];
    __shared__ int gbase[9];
    int tid = threadIdx.x;
    int lane = tid & 63, wave = tid >> 6;
    int i = blockIdx.x * blockDim.x + tid;
    int band = -1, rank = 0;
    if (i < B) band = (int)x[i * 18 + 17];
    for (int k = 0; k < 9; ++k) {
        unsigned long long m = __ballot(band == k);
        if (band == k) rank = __popcll(m & ((1ull << lane) - 1ull));
        if (lane == 0) wcnt[wave][k] = __popcll(m);
    }
    __syncthreads();
    if (tid < 9) {
        int k = tid, run = 0;
        for (int w = 0; w < 4; ++w) { wpre[w][k] = run; run += wcnt[w][k]; }
        gbase[k] = (run > 0) ? atomicAdd(&gsc[k], run) : 0;
    }
    __syncthreads();
    if (i < B && band >= 0) {
        int pos = goff[band] + gbase[band] + wpre[wave][band] + rank;
        perm[pos] = i;
    }
}

// ---------------- fused main kernel: 64 rows / block, 8 waves, uniform band ----------------
// 512 threads (8 waves): halves per-wave slices and doubles waves/CU vs round-4's
// 256-thread version (12 -> 16 waves/CU) to hide weight-load + LDS latency.
// __launch_bounds__(512,4): cap 128 VGPR, no spill (round-3 lesson).
__global__ __launch_bounds__(512, 4) void k_main(
                       const float* __restrict__ x,
                       const int* __restrict__ perm,
                       const int* __restrict__ blk_band,
                       const int* __restrict__ blk_start,
                       const int* __restrict__ blk_nrows,
                       const u16* __restrict__ W1p, const u16* __restrict__ W2f,
                       const u16* __restrict__ HWf,
                       const u16* __restrict__ SWf, const u16* __restrict__ STWf,
                       const float* __restrict__ tb1, const float* __restrict__ tb2,
                       const float* __restrict__ hb1, const float* __restrict__ hw2,
                       const float* __restrict__ hb2,
                       const float* __restrict__ sb1, const float* __restrict__ sw2,
                       const float* __restrict__ sb2,
                       const float* __restrict__ stb1, const float* __restrict__ stw2,
                       const float* __restrict__ stb2,
                       const float* __restrict__ sp,
                       const float* __restrict__ sun_b1, const float* __restrict__ sun_b2,
                       const float* __restrict__ storm_b1, const float* __restrict__ storm_b2,
                       float* __restrict__ out)
{
    int bb = blk_band[blockIdx.x];
    if (bb < 0) return;
    int rstart = blk_start[blockIdx.x];
    int nrows  = blk_nrows[blockIdx.x];

    __shared__ u16 xA[64][32];
    __shared__ int rowsL[64];
    __shared__ float sfiL[64], kpL[64];
    __shared__ u16 buf[2][64][136];            // chunk dbuf; aliased as t[64][264] later
    __shared__ float headp[8][64], sunp[4][64], stormp[4][64];

    int tid = threadIdx.x;
    int lane = tid & 63, wave = tid >> 6;      // wave 0..7
    int quad = lane >> 4, l15 = lane & 15;

    if (tid < 64) {
        int r = rstart + (tid < nrows ? tid : 0);
        rowsL[tid] = perm[r];
    }
    for (int i = tid; i < 64 * 32; i += 512) ((u16*)xA)[i] = 0;
    __syncthreads();
    for (int i = tid; i < 64 * 18; i += 512) {
        int r = i / 18, c = i - r * 18;
        float v = x[rowsL[r] * 18 + c];
        if (c < 15) xA[r][c] = f2b(v);
        else if (c == 15) sfiL[r] = v;
        else if (c == 16) kpL[r] = v;
    }
    __syncthreads();

    // A-fragments of x: A[m=mt*16+l15][k=quad*8+j]
    bf16x8 ax[4];
#pragma unroll
    for (int mt = 0; mt < 4; ++mt)
        ax[mt] = *(const bf16x8*)&xA[mt * 16 + l15][quad * 8];

    f32x4 acc2[2][4] = {};   // [ntl][mt], wave cols = wave*32 + ntl*16

    for (int c = 0; c < 4; ++c) {
        // ---- Phase 1: this wave's 16 cols of chunk c: ncol = c*128 + wave*16 + l15
        f32x4 acc1[4] = {};
        {
            int ncol = c * 128 + wave * 16 + l15;
            bf16x8 bw = *(const bf16x8*)&W1p[ncol * 32 + quad * 8];
#pragma unroll
            for (int mt = 0; mt < 4; ++mt)
                acc1[mt] = MFMA16(ax[mt], bw, acc1[mt]);
        }
        u16 (*bufc)[136] = buf[c & 1];
        {
            int ccol = wave * 16 + l15;
            float bias = tb1[c * 128 + ccol];
#pragma unroll
            for (int mt = 0; mt < 4; ++mt)
#pragma unroll
                for (int r = 0; r < 4; ++r)
                    bufc[mt * 16 + quad * 4 + r][ccol] = f2b(mish_f(acc1[mt][r] + bias));
        }
        __syncthreads();
        // ---- Phase 2 partial: acc2 += chunk @ W2 (this wave's 32 cols), FM loads
        for (int ks = 0; ks < 4; ++ks) {
            bf16x8 a2[4];
#pragma unroll
            for (int mt = 0; mt < 4; ++mt)
                a2[mt] = *(const bf16x8*)&bufc[mt * 16 + l15][ks * 32 + quad * 8];
            int kb = c * 4 + ks;
#pragma unroll
            for (int ntl = 0; ntl < 2; ++ntl) {
                int nt = wave * 2 + ntl;
                bf16x8 bw = *(const bf16x8*)&W2f[((nt * 16 + kb) << 9) + lane * 8];
#pragma unroll
                for (int mt = 0; mt < 4; ++mt)
                    acc2[ntl][mt] = MFMA16(a2[mt], bw, acc2[ntl][mt]);
            }
        }
    }
    __syncthreads();   // all P2 reads of buf done before aliasing with t

    // ---- t = mish(acc2 + tb2) -> LDS t[64][264] (aliases buf)
    u16 (*tmat)[264] = (u16(*)[264])buf;
#pragma unroll
    for (int ntl = 0; ntl < 2; ++ntl) {
        int col = wave * 32 + ntl * 16 + l15;
        float bias = tb2[col];
#pragma unroll
        for (int mt = 0; mt < 4; ++mt)
#pragma unroll
            for (int r = 0; r < 4; ++r)
                tmat[mt * 16 + quad * 4 + r][col] = f2b(mish_f(acc2[ntl][mt][r] + bias));
    }
    __syncthreads();

    // ---- Phase 3: head ntile = wave (8x16 = 128 cols); gate: waves 0-3 sun nt=wave,
    //      waves 4-7 storm nt=wave-4. FM loads, K=256 (8 kblocks).
    f32x4 acch[4] = {}, accg[4] = {};
    const u16* Hw = HWf + bb * 32768;
    const u16* Gw = (wave < 4) ? SWf : STWf;
    int gnt = wave & 3;
    for (int kb = 0; kb < 8; ++kb) {
        bf16x8 a3[4];
#pragma unroll
        for (int mt = 0; mt < 4; ++mt)
            a3[mt] = *(const bf16x8*)&tmat[mt * 16 + l15][kb * 32 + quad * 8];
        bf16x8 bh = *(const bf16x8*)&Hw[((wave * 8 + kb) << 9) + lane * 8];
        bf16x8 bg = *(const bf16x8*)&Gw[((gnt * 8 + kb) << 9) + lane * 8];
#pragma unroll
        for (int mt = 0; mt < 4; ++mt) {
            acch[mt] = MFMA16(a3[mt], bh, acch[mt]);
            accg[mt] = MFMA16(a3[mt], bg, accg[mt]);
        }
    }

    // head epilogue: this wave's 16 cols, dot with hw2[band]
    float hsum[4][4];
    {
        int col = wave * 16 + l15;
        float hb = hb1[bb * 128 + col];
        float wv = hw2[bb * 128 + col];
#pragma unroll
        for (int mt = 0; mt < 4; ++mt)
#pragma unroll
            for (int r = 0; r < 4; ++r)
                hsum[mt][r] = mish_f(acch[mt][r] + hb) * wv;
    }
    // gate epilogue: this wave's 16 cols of sun or storm
    float gsum[4][4];
    {
        int n = gnt * 16 + l15;
        float gb = (wave < 4) ? sb1[n] : stb1[n];
        float gw = (wave < 4) ? sw2[n] : stw2[n];
#pragma unroll
        for (int mt = 0; mt < 4; ++mt)
#pragma unroll
            for (int r = 0; r < 4; ++r)
                gsum[mt][r] = mish_f(accg[mt][r] + gb) * gw;
    }
#pragma unroll
    for (int off = 1; off < 16; off <<= 1)
#pragma unroll
        for (int mt = 0; mt < 4; ++mt)
#pragma unroll
            for (int r = 0; r < 4; ++r) {
                hsum[mt][r] += __shfl_xor(hsum[mt][r], off, 64);
                gsum[mt][r] += __shfl_xor(gsum[mt][r], off, 64);
            }
    if (l15 == 0)
#pragma unroll
        for (int mt = 0; mt < 4; ++mt)
#pragma unroll
            for (int r = 0; r < 4; ++r) {
                int row = mt * 16 + quad * 4 + r;
                headp[wave][row] = hsum[mt][r];
                if (wave < 4) sunp[wave][row] = gsum[mt][r];
                else          stormp[wave - 4][row] = gsum[mt][r];
            }
    __syncthreads();

    // ---- final scalar math per row (fp32 output)
    if (tid < 64 && tid < nrows) {
        int row = tid;
        float head = hb2[bb];
#pragma unroll
        for (int w = 0; w < 8; ++w) head += headp[w][row];
        float sl = sb2[0], tl = stb2[0];
#pragma unroll
        for (int w = 0; w < 4; ++w) { sl += sunp[w][row]; tl += stormp[w][row]; }
        float sg = sigmoid_f(sl);
        float tg = sigmoid_f(tl);
        float v1 = sfiL[row], v2 = kpL[row];
        float sun_val = sun_b2[0], storm_val = storm_b2[0];
#pragma unroll
        for (int j = 0; j < 8; ++j) {
            sun_val   += tanh_f(v1 * sp[j]      + sun_b1[j])   * sp[8 + j];
            storm_val += tanh_f(v2 * sp[16 + j] + storm_b1[j]) * sp[24 + j];
        }
        out[rowsL[row]] = head + sg * sun_val + tg * storm_val;
    }
}

// ---------------- fallback: pure-VALU scalar kernel (used if ws too small) ----------------
__global__ __launch_bounds__(64) void k_simple(
    const float* __restrict__ x,
    const float* __restrict__ tw1, const float* __restrict__ tb1,
    const float* __restrict__ tw2, const float* __restrict__ tb2,
    const float* __restrict__ hw1, const float* __restrict__ hb1,
    const float* __restrict__ hw2, const float* __restrict__ hb2,
    const float* __restrict__ sw1, const float* __restrict__ sb1,
    const float* __restrict__ sw2, const float* __restrict__ sb2,
    const float* __restrict__ stw1, const float* __restrict__ stb1,
    const float* __restrict__ stw2, const float* __restrict__ stb2,
    const float* __restrict__ sun_w1, const float* __restrict__ sun_b1,
    const float* __restrict__ sun_w2, const float* __restrict__ sun_b2,
    const float* __restrict__ storm_w1, const float* __restrict__ storm_b1,
    const float* __restrict__ storm_w2, const float* __restrict__ storm_b2,
    float* __restrict__ out)
{
    __shared__ u16 t_lds[256 * 64];

    const int lane = threadIdx.x;
    const int r = blockIdx.x * 64 + lane;

    float xr[15];
#pragma unroll
    for (int k = 0; k < 15; ++k) xr[k] = x[r * 18 + k];
    const float sfi = x[r * 18 + 15];
    const float kp  = x[r * 18 + 16];
    const int band  = (int)x[r * 18 + 17];

    for (int tc = 0; tc < 4; ++tc) {
        float acc[64];
#pragma unroll
        for (int j = 0; j < 64; ++j) acc[j] = 0.0f;
        for (int n = 0; n < 512; ++n) {
            float p = tb1[n];
#pragma unroll
            for (int k = 0; k < 15; ++k) p += xr[k] * tw1[k * 512 + n];
            const float a1n = mish_f(p);
            const float* w2 = &tw2[n * 256 + tc * 64];
#pragma unroll
            for (int j = 0; j < 64; ++j) acc[j] += a1n * w2[j];
        }
#pragma unroll
        for (int j = 0; j < 64; ++j)
            t_lds[(tc * 64 + j) * 64 + lane] = f2b(mish_f(acc[j] + tb2[tc * 64 + j]));
    }
    __syncthreads();

    float head_val = 0.0f;
    for (int g = 0; g < 9; ++g) {
        float hs = 0.0f;
        for (int hc = 0; hc < 2; ++hc) {
            float pre[64];
#pragma unroll
            for (int j = 0; j < 64; ++j) pre[j] = 0.0f;
            for (int d = 0; d < 256; ++d) {
                const float td = b2f(t_lds[d * 64 + lane]);
                const float* wv = &hw1[g * 32768 + d * 128 + hc * 64];
#pragma unroll
                for (int j = 0; j < 64; ++j) pre[j] += td * wv[j];
            }
#pragma unroll
            for (int j = 0; j < 64; ++j) {
                const int h = hc * 64 + j;
                hs += mish_f(pre[j] + hb1[g * 128 + h]) * hw2[g * 128 + h];
            }
        }
        head_val += (band == g) ? (hs + hb2[g]) : 0.0f;
    }

    float pre_s[64], pre_t[64];
#pragma unroll
    for (int j = 0; j < 64; ++j) { pre_s[j] = 0.0f; pre_t[j] = 0.0f; }
    for (int d = 0; d < 256; ++d) {
        const float td = b2f(t_lds[d * 64 + lane]);
        const float* ws1 = &sw1[d * 64];
        const float* wt1 = &stw1[d * 64];
#pragma unroll
        for (int j = 0; j < 64; ++j) {
            pre_s[j] += td * ws1[j];
            pre_t[j] += td * wt1[j];
        }
    }
    float ls = sb2[0], lt = stb2[0];
#pragma unroll
    for (int j = 0; j < 64; ++j) {
        ls += mish_f(pre_s[j] + sb1[j]) * sw2[j];
        lt += mish_f(pre_t[j] + stb1[j]) * stw2[j];
    }
    const float sg = sigmoid_f(ls);
    const float tg = sigmoid_f(lt);

    float sun_val = sun_b2[0], storm_val = storm_b2[0];
#pragma unroll
    for (int j = 0; j < 8; ++j) {
        sun_val   += tanh_f(sfi * splus(sun_w1[j])  + sun_b1[j])   * splus(sun_w2[j]);
        storm_val += tanh_f(kp * splus(storm_w1[j]) + storm_b1[j]) * splus(storm_w2[j]);
    }

    out[r] = head_val + sg * sun_val + tg * storm_val;
}

extern "C" void kernel_launch(void* const* d_in, const int* in_sizes, int n_in,
                              void* d_out, int out_size, void* d_ws, size_t ws_size,
                              hipStream_t stream) {
    (void)n_in; (void)out_size;
    const float* x        = (const float*)d_in[0];
    const float* tw1      = (const float*)d_in[1];
    const float* tb1      = (const float*)d_in[2];
    const float* tw2      = (const float*)d_in[3];
    const float* tb2      = (const float*)d_in[4];
    const float* hw1      = (const float*)d_in[5];
    const float* hb1      = (const float*)d_in[6];
    const float* hw2      = (const float*)d_in[7];
    const float* hb2      = (const float*)d_in[8];
    const float* sw1      = (const float*)d_in[9];
    const float* sb1      = (const float*)d_in[10];
    const float* sw2      = (const float*)d_in[11];
    const float* sb2      = (const float*)d_in[12];
    const float* stw1     = (const float*)d_in[13];
    const float* stb1     = (const float*)d_in[14];
    const float* stw2     = (const float*)d_in[15];
    const float* stb2     = (const float*)d_in[16];
    const float* sun_w1   = (const float*)d_in[17];
    const float* sun_b1   = (const float*)d_in[18];
    const float* sun_w2   = (const float*)d_in[19];
    const float* sun_b2   = (const float*)d_in[20];
    const float* storm_w1 = (const float*)d_in[21];
    const float* storm_b1 = (const float*)d_in[22];
    const float* storm_w2 = (const float*)d_in[23];
    const float* storm_b2 = (const float*)d_in[24];

    const int B = in_sizes[0] / 18;

    if (ws_size < (size_t)WS_NEEDED) {
        k_simple<<<B / 64, 64, 0, stream>>>(x, tw1, tb1, tw2, tb2, hw1, hb1, hw2, hb2,
                                            sw1, sb1, sw2, sb2, stw1, stb1, stw2, stb2,
                                            sun_w1, sun_b1, sun_w2, sun_b2,
                                            storm_w1, storm_b1, storm_w2, storm_b2,
                                            (float*)d_out);
        return;
    }

    char* ws = (char*)d_ws;
    int*   perm      = (int*)(ws + WS_PERM);
    int*   gsc       = (int*)(ws + WS_GSC);
    int*   goff      = (int*)(ws + WS_GOFF);
    int*   blk_band  = (int*)(ws + WS_BBAND);
    int*   blk_start = (int*)(ws + WS_BSTART);
    int*   blk_nrows = (int*)(ws + WS_BNROWS);
    float* sp        = (float*)(ws + WS_SP);
    int*   gpart     = (int*)(ws + WS_GPART);
    u16*   W1p       = (u16*)(ws + WS_W1P);
    u16*   W2f       = (u16*)(ws + WS_W2F);
    u16*   HWf       = (u16*)(ws + WS_HW1F);
    u16*   SWf       = (u16*)(ws + WS_SWF);
    u16*   STWf      = (u16*)(ws + WS_STWF);

    int nblk = B / 64 + 16;

    k_pack<<<PACK_BLOCKS, 256, 0, stream>>>(x, B, tw1, tw2, hw1, sw1, stw1,
                                            sun_w1, sun_w2, storm_w1, storm_w2,
                                            W1p, W2f, HWf, SWf, STWf, sp, gpart);
    k_table<<<1, 256, 0, stream>>>(gpart, goff, gsc, blk_band, blk_start, blk_nrows, nblk);
    k_scatter<<<(B + 255) / 256, 256, 0, stream>>>(x, goff, gsc, perm, B);
    k_main<<<nblk, 512, 0, stream>>>(x, perm, blk_band, blk_start, blk_nrows,
                                     W1p, W2f, HWf, SWf, STWf,
                                     tb1, tb2, hb1, hw2, hb2,
                                     sb1, sw2, sb2, stb1, stw2, stb2,
                                     sp, sun_b1, sun_b2, storm_b1, storm_b2,
                                     (float*)d_out);
}